// Round 5
// baseline (10.856 us; speedup 1.0000x reference)
//
#include <hip/hip_runtime.h>
#include <math.h>

#define PCOUNT 512
#define IMG_W 256
#define IMG_H 256
#define TANX 0.5f
#define TANY 0.5f
#define NEARP 0.2f
#define BLUR 0.3f
#define AMIN (1.0f/255.0f)
#define AMAX 0.99f

// One block per 16x16 tile, 1024 threads (16 waves).
// t<512: preprocess one gaussian (redundant per block; all CUs in parallel),
// ballot-compact survivors (exact alpha>=1/255 ellipse vs tile), direct
// stable-rank scatter into depth-sorted LDS order, then 8-way segmented
// front-to-back composite (2 pixels/thread) combined via over-operator
// associativity.
__global__ __launch_bounds__(1024) void fused_raster_kernel(
    const float* __restrict__ means, const float* __restrict__ opac,
    const float* __restrict__ scales, const float* __restrict__ rots,
    const float* __restrict__ cols, const float* __restrict__ vm,
    const float* __restrict__ pm, const float* __restrict__ bg,
    float* __restrict__ out)
{
    __shared__ float s_params[PCOUNT * 12];   // sorted: A,B,C,px,py,opa,r,g,b
    __shared__ float s_depth[PCOUNT];         // depth at compaction slot
    __shared__ float4 s_part[8][256];         // per-segment (cr,cg,cb,T)
    __shared__ int s_wcnt[16];

    int t = threadIdx.x;
    int wave = t >> 6, lane = t & 63;
    int tileX = blockIdx.x & 15, tileY = blockIdx.x >> 4;
    float tx0 = (float)(tileX << 4), tx1 = tx0 + 15.0f;
    float ty0 = (float)(tileY << 4), ty1 = ty0 + 15.0f;

    // ---- preprocess (one gaussian per thread, t < 512) ----
    bool hit = false;
    float conA = 0, conB = 0, conC = 0, px = 0, py = 0, opa_eff = 0, tz = 0;
    float colr = 0, colg = 0, colb = 0;
    int g = t;
    if (t < PCOUNT) {
        // issue all global loads up front (in flight together; caches are cold)
        float mx = means[3*g], my = means[3*g+1], mz = means[3*g+2];
        float op = opac[g];
        float sc0 = scales[3*g], sc1 = scales[3*g+1], sc2 = scales[3*g+2];
        float4 q4 = *(const float4*)(rots + 4*g);
        colr = cols[3*g]; colg = cols[3*g+1]; colb = cols[3*g+2];

        float o = 1.0f / (1.0f + __expf(-op));
        float sx = __expf(sc0), sy = __expf(sc1), sz = __expf(sc2);

        float qr = q4.x, qx = q4.y, qy = q4.z, qz = q4.w;
        float qn = fmaxf(sqrtf(qr*qr + qx*qx + qy*qy + qz*qz), 1e-12f);
        float qi = 1.0f/qn;
        qr *= qi; qx *= qi; qy *= qi; qz *= qi;

        float R00 = 1.0f-2.0f*(qy*qy+qz*qz), R01 = 2.0f*(qx*qy - qr*qz), R02 = 2.0f*(qx*qz + qr*qy);
        float R10 = 2.0f*(qx*qy + qr*qz), R11 = 1.0f-2.0f*(qx*qx+qz*qz), R12 = 2.0f*(qy*qz - qr*qx);
        float R20 = 2.0f*(qx*qz - qr*qy), R21 = 2.0f*(qy*qz + qr*qx), R22 = 1.0f-2.0f*(qx*qx+qy*qy);

        float s0 = sx*sx, s1 = sy*sy, s2 = sz*sz;
        float c00 = R00*R00*s0 + R01*R01*s1 + R02*R02*s2;
        float c01 = R00*R10*s0 + R01*R11*s1 + R02*R12*s2;
        float c02 = R00*R20*s0 + R01*R21*s1 + R02*R22*s2;
        float c11 = R10*R10*s0 + R11*R11*s1 + R12*R12*s2;
        float c12 = R10*R20*s0 + R11*R21*s1 + R12*R22*s2;
        float c22 = R20*R20*s0 + R21*R21*s1 + R22*R22*s2;

        float tvx = vm[0]*mx + vm[1]*my + vm[2]*mz + vm[3];
        float tvy = vm[4]*mx + vm[5]*my + vm[6]*mz + vm[7];
        tz = vm[8]*mx + vm[9]*my + vm[10]*mz + vm[11];
        bool valid = tz > NEARP;
        float tzc = valid ? tz : 1.0f;

        float limx = 1.3f*TANX, limy = 1.3f*TANY;
        float txz = fminf(fmaxf(tvx/tzc, -limx), limx)*tzc;
        float tyz = fminf(fmaxf(tvy/tzc, -limy), limy)*tzc;

        float fx = (float)IMG_W/(2.0f*TANX), fy = (float)IMG_H/(2.0f*TANY);
        float J00 = fx/tzc, J02 = -fx*txz/(tzc*tzc);
        float J11 = fy/tzc, J12 = -fy*tyz/(tzc*tzc);

        float T00 = J00*vm[0] + J02*vm[8];
        float T01 = J00*vm[1] + J02*vm[9];
        float T02 = J00*vm[2] + J02*vm[10];
        float T10 = J11*vm[4] + J12*vm[8];
        float T11 = J11*vm[5] + J12*vm[9];
        float T12 = J11*vm[6] + J12*vm[10];

        float M00 = T00*c00 + T01*c01 + T02*c02;
        float M01 = T00*c01 + T01*c11 + T02*c12;
        float M02 = T00*c02 + T01*c12 + T02*c22;
        float M10 = T10*c00 + T11*c01 + T12*c02;
        float M11 = T10*c01 + T11*c11 + T12*c12;
        float M12 = T10*c02 + T11*c12 + T12*c22;
        float v00 = M00*T00 + M01*T01 + M02*T02 + BLUR;
        float v01 = M00*T10 + M01*T11 + M02*T12;
        float v11 = M10*T10 + M11*T11 + M12*T12 + BLUR;

        float det = v00*v11 - v01*v01;
        det = (det == 0.0f) ? 1.0f : det;
        float idet = 1.0f/det;
        conA = v11*idet; conB = -v01*idet; conC = v00*idet;

        float ph0 = pm[0]*mx + pm[1]*my + pm[2]*mz + pm[3];
        float ph1 = pm[4]*mx + pm[5]*my + pm[6]*mz + pm[7];
        float ph3 = pm[12]*mx + pm[13]*my + pm[14]*mz + pm[15];
        float pw = 1.0f/(ph3 + 1e-7f);
        px = ((ph0*pw + 1.0f)*(float)IMG_W - 1.0f)*0.5f;
        py = ((ph1*pw + 1.0f)*(float)IMG_H - 1.0f)*0.5f;

        opa_eff = valid ? o : 0.0f;

        float oa = opa_eff * 255.0f;
        if (oa > 1.0f) {
            float r2 = 2.0f * __logf(oa);
            float dxm = sqrtf(r2 * v00) + 1.0f;
            float dym = sqrtf(r2 * v11) + 1.0f;
            hit = (px - dxm <= tx1) & (px + dxm >= tx0) &
                  (py - dym <= ty1) & (py + dym >= ty0);
        }
    }

    // ---- ordered ballot compaction: depth -> slot ----
    unsigned long long m = __ballot(hit);
    int rnk = __popcll(m & ((1ull << lane) - 1ull));
    if (lane == 0) s_wcnt[wave] = __popcll(m);
    __syncthreads();

    int off = 0, total = 0;
    #pragma unroll
    for (int w = 0; w < 16; ++w) {
        int c = s_wcnt[w];
        off   += (w < wave) ? c : 0;
        total += c;
    }
    int slot = off + rnk;
    if (hit) s_depth[slot] = tz;
    __syncthreads();

    // ---- direct stable-rank scatter into sorted order ----
    if (hit) {
        int rank = 0;
        for (int j = 0; j < total; ++j) {
            float dj = s_depth[j];
            rank += (int)((dj < tz) || (dj == tz && j < slot));
        }
        float* p = &s_params[rank * 12];
        p[0] = conA; p[1] = conB; p[2] = conC; p[3] = px;
        p[4] = py;   p[5] = opa_eff;
        p[6] = colr; p[7] = colg; p[8] = colb;
    }
    __syncthreads();

    // ---- 8-way segmented composite, 2 pixels per thread ----
    int p0i = t & 127, seg = t >> 7;
    int lx0 = p0i & 15, ly0 = p0i >> 4;          // pixel p0i
    int ly1 = (p0i + 128) >> 4;                  // pixel p0i+128 (same lx)
    float fx0 = tx0 + (float)lx0;
    float fy0 = ty0 + (float)ly0, fy1 = ty0 + (float)ly1;

    int seglen = (total + 7) >> 3;
    int i0 = seg * seglen;
    int i1 = min(i0 + seglen, total);

    float Ta = 1.0f, ar = 0.0f, ag = 0.0f, ab = 0.0f;
    float Tb = 1.0f, br = 0.0f, bgn = 0.0f, bb = 0.0f;
    for (int i = i0; i < i1; ++i) {
        const float* pp = &s_params[i * 12];
        float4 q0 = *(const float4*)(pp);      // A,B,C,px
        float4 q1 = *(const float4*)(pp + 4);  // py,opa,r,g
        float qb  = pp[8];

        float dx = q0.w - fx0;
        float dya = q1.x - fy0, dyb = q1.x - fy1;

        float pwa = -0.5f*(q0.x*dx*dx + q0.z*dya*dya) - q0.y*dx*dya;
        float pwb = -0.5f*(q0.x*dx*dx + q0.z*dyb*dyb) - q0.y*dx*dyb;

        float ala = q1.y * __expf(pwa);
        float alb = q1.y * __expf(pwb);
        ala = ((pwa <= 0.0f) & (ala >= AMIN)) ? fminf(ala, AMAX) : 0.0f;
        alb = ((pwb <= 0.0f) & (alb >= AMIN)) ? fminf(alb, AMAX) : 0.0f;

        float wa = ala * Ta, wb = alb * Tb;
        ar += wa * q1.z;  ag += wa * q1.w;  ab += wa * qb;
        br += wb * q1.z;  bgn += wb * q1.w; bb += wb * qb;
        Ta *= (1.0f - ala);
        Tb *= (1.0f - alb);
    }
    s_part[seg][p0i]       = make_float4(ar, ag, ab, Ta);
    s_part[seg][p0i + 128] = make_float4(br, bgn, bb, Tb);
    __syncthreads();

    // ---- combine 8 segments + store (t < 256) ----
    if (t < 256) {
        float4 acc = s_part[7][t];
        #pragma unroll
        for (int s = 6; s >= 0; --s) {
            float4 r = s_part[s][t];
            acc.x = r.x + r.w * acc.x;
            acc.y = r.y + r.w * acc.y;
            acc.z = r.z + r.w * acc.z;
            acc.w = r.w * acc.w;
        }
        int x = (tileX << 4) + (t & 15), y = (tileY << 4) + (t >> 4);
        int o = (y*IMG_W + x)*3;
        out[o+0] = acc.x + acc.w*bg[0];
        out[o+1] = acc.y + acc.w*bg[1];
        out[o+2] = acc.z + acc.w*bg[2];
    }
}

extern "C" void kernel_launch(void* const* d_in, const int* in_sizes, int n_in,
                              void* d_out, int out_size, void* d_ws, size_t ws_size,
                              hipStream_t stream) {
    const float* means  = (const float*)d_in[0];
    const float* opac   = (const float*)d_in[1];
    const float* scales = (const float*)d_in[2];
    const float* rots   = (const float*)d_in[3];
    const float* cols   = (const float*)d_in[4];
    const float* vm     = (const float*)d_in[5];
    const float* pm     = (const float*)d_in[6];
    const float* bg     = (const float*)d_in[8];

    fused_raster_kernel<<<256, 1024, 0, stream>>>(
        means, opac, scales, rots, cols, vm, pm, bg, (float*)d_out);
}